// Round 1
// baseline (108.025 us; speedup 1.0000x reference)
//
#include <hip/hip_runtime.h>
#include <hip/hip_bf16.h>

// Problem constants (AgentModel): B=8, N=256, TD=128, LH=128, H=128, A=5, L=2
constexpr int Bc = 8;
constexpr int Nc = 256;
constexpr int Hc = 128;   // hidden
constexpr int Ac = 5;
constexpr int Mc = Bc * Nc;     // 2048 rows
constexpr int ROWS = 16;        // rows per GEMM block

// ---------------------------------------------------------------------------
// Encoder: h[m,o] = relu( sum_d x[m,d] * encW[o,d] + encb[o] ), d in [0,256)
// x row = concat(theta row (128), cell row (128))
// ---------------------------------------------------------------------------
__global__ __launch_bounds__(256) void enc_kernel(
    const float* __restrict__ theta, const float* __restrict__ cell,
    const float* __restrict__ W, const float* __restrict__ bias,
    float* __restrict__ h) {
  __shared__ float xs[ROWS][256];
  const int m0 = blockIdx.x * ROWS;
  const int tid = threadIdx.x;

  // stage 16 rows x 256 floats (theta|cell), float4, coalesced
  for (int idx = tid * 4; idx < ROWS * 256; idx += 256 * 4) {
    int r = idx >> 8;
    int d = idx & 255;
    const float* src = (d < 128) ? (theta + (m0 + r) * 128 + d)
                                 : (cell + (m0 + r) * 128 + (d - 128));
    *reinterpret_cast<float4*>(&xs[r][d]) = *reinterpret_cast<const float4*>(src);
  }
  __syncthreads();

  const int o = tid & 127;
  const int rg = tid >> 7;  // 0..1 -> rows rg*8 .. rg*8+7
  float acc[8] = {0, 0, 0, 0, 0, 0, 0, 0};
  const float* wrow = W + o * 256;
#pragma unroll 4
  for (int k = 0; k < 256; k += 4) {
    float4 w = *reinterpret_cast<const float4*>(wrow + k);
#pragma unroll
    for (int r = 0; r < 8; ++r) {
      const float* xr = &xs[rg * 8 + r][k];
      acc[r] += w.x * xr[0] + w.y * xr[1] + w.z * xr[2] + w.w * xr[3];
    }
  }
  const float bo = bias[o];
#pragma unroll
  for (int r = 0; r < 8; ++r) {
    h[(m0 + rg * 8 + r) * Hc + o] = fmaxf(acc[r] + bo, 0.f);
  }
}

// ---------------------------------------------------------------------------
// pj/pi: pj[m,o] = sum_h h[m,h]*msgW[o,h]        (msgW row o, cols [0,128))
//        pi[m,o] = sum_h h[m,h]*msgW[o,128+h]    (msgW row o, cols [128,256))
// One kernel: thread o in [0,256): o<128 -> pj col o, else pi col o-128
// ---------------------------------------------------------------------------
__global__ __launch_bounds__(256) void pjpi_kernel(
    const float* __restrict__ h, const float* __restrict__ msgW,
    float* __restrict__ pj, float* __restrict__ pi) {
  __shared__ float xs[ROWS][128];
  const int m0 = blockIdx.x * ROWS;
  const int tid = threadIdx.x;

  for (int idx = tid * 4; idx < ROWS * 128; idx += 256 * 4) {
    int r = idx >> 7;
    int d = idx & 127;
    *reinterpret_cast<float4*>(&xs[r][d]) =
        *reinterpret_cast<const float4*>(h + (m0 + r) * Hc + d);
  }
  __syncthreads();

  const int o = tid;
  const float* wrow = (o < 128) ? (msgW + o * 256) : (msgW + (o - 128) * 256 + 128);
  float acc[ROWS];
#pragma unroll
  for (int r = 0; r < ROWS; ++r) acc[r] = 0.f;
#pragma unroll 2
  for (int k = 0; k < 128; k += 4) {
    float4 w = *reinterpret_cast<const float4*>(wrow + k);
#pragma unroll
    for (int r = 0; r < ROWS; ++r) {
      const float* xr = &xs[r][k];
      acc[r] += w.x * xr[0] + w.y * xr[1] + w.z * xr[2] + w.w * xr[3];
    }
  }
  float* dst = (o < 128) ? pj : pi;
  const int oc = o & 127;
#pragma unroll
  for (int r = 0; r < ROWS; ++r) {
    dst[(m0 + r) * Hc + oc] = acc[r];
  }
}

// ---------------------------------------------------------------------------
// Aggregation: agg[b,i,o] =
//   ( sum_j relu(pj[b,j,o] + pi[b,i,o] + mb[o]) - relu(pj[b,i,o]+pi[b,i,o]+mb[o]) ) / 255
// Block: one batch b, 8 i-rows, all 128 o. Stage pj in 64-row tiles.
// ---------------------------------------------------------------------------
__global__ __launch_bounds__(256) void agg_kernel(
    const float* __restrict__ pj, const float* __restrict__ pi,
    const float* __restrict__ mb, float* __restrict__ agg) {
  __shared__ float pjt[64][128];  // 32 KB
  const int b = blockIdx.x >> 5;   // 8 batches
  const int it = blockIdx.x & 31;  // 32 i-tiles of 8 rows
  const int i0 = it * 8;
  const int tid = threadIdx.x;
  const int o = tid & 127;
  const int ig = tid >> 7;  // rows ig*4 .. ig*4+3

  const float* pjb = pj + b * Nc * Hc;
  const float* pib = pi + b * Nc * Hc;
  const float mbo = mb[o];

  float s[4], diag[4], acc[4];
#pragma unroll
  for (int r = 0; r < 4; ++r) {
    int i = i0 + ig * 4 + r;
    s[r] = pib[i * Hc + o] + mbo;
    diag[r] = pjb[i * Hc + o];
    acc[r] = 0.f;
  }

  for (int jt = 0; jt < Nc; jt += 64) {
    __syncthreads();
    for (int idx = tid * 4; idx < 64 * 128; idx += 256 * 4) {
      int r = idx >> 7;
      int d = idx & 127;
      *reinterpret_cast<float4*>(&pjt[r][d]) =
          *reinterpret_cast<const float4*>(pjb + (jt + r) * Hc + d);
    }
    __syncthreads();
#pragma unroll 4
    for (int j = 0; j < 64; ++j) {
      float v = pjt[j][o];
#pragma unroll
      for (int r = 0; r < 4; ++r) acc[r] += fmaxf(v + s[r], 0.f);
    }
  }

#pragma unroll
  for (int r = 0; r < 4; ++r) {
    int i = i0 + ig * 4 + r;
    float a = (acc[r] - fmaxf(diag[r] + s[r], 0.f)) * (1.f / 255.f);
    agg[(b * Nc + i) * Hc + o] = a;
  }
}

// ---------------------------------------------------------------------------
// Update: h[m,o] = relu( sum_k (h[m,k]+agg[m,k]) * W[o,k] + bias[o] )  in-place
// ---------------------------------------------------------------------------
__global__ __launch_bounds__(256) void upd_kernel(
    float* __restrict__ h, const float* __restrict__ agg,
    const float* __restrict__ W, const float* __restrict__ bias) {
  __shared__ float xs[ROWS][128];
  const int m0 = blockIdx.x * ROWS;
  const int tid = threadIdx.x;

  for (int idx = tid * 4; idx < ROWS * 128; idx += 256 * 4) {
    int r = idx >> 7;
    int d = idx & 127;
    float4 a = *reinterpret_cast<const float4*>(h + (m0 + r) * Hc + d);
    float4 g = *reinterpret_cast<const float4*>(agg + (m0 + r) * Hc + d);
    float4 v = make_float4(a.x + g.x, a.y + g.y, a.z + g.z, a.w + g.w);
    *reinterpret_cast<float4*>(&xs[r][d]) = v;
  }
  __syncthreads();

  const int o = tid & 127;
  const int rg = tid >> 7;
  float acc[8] = {0, 0, 0, 0, 0, 0, 0, 0};
  const float* wrow = W + o * 128;
#pragma unroll 2
  for (int k = 0; k < 128; k += 4) {
    float4 w = *reinterpret_cast<const float4*>(wrow + k);
#pragma unroll
    for (int r = 0; r < 8; ++r) {
      const float* xr = &xs[rg * 8 + r][k];
      acc[r] += w.x * xr[0] + w.y * xr[1] + w.z * xr[2] + w.w * xr[3];
    }
  }
  const float bo = bias[o];
#pragma unroll
  for (int r = 0; r < 8; ++r) {
    h[(m0 + rg * 8 + r) * Hc + o] = fmaxf(acc[r] + bo, 0.f);
  }
}

// ---------------------------------------------------------------------------
// Head: z = relu(h @ W1^T + b1); logits = z @ W2^T + b2  (A=5)
// ---------------------------------------------------------------------------
__global__ __launch_bounds__(256) void head_kernel(
    const float* __restrict__ h, const float* __restrict__ W1,
    const float* __restrict__ b1, const float* __restrict__ W2,
    const float* __restrict__ b2, float* __restrict__ out) {
  __shared__ float xs[ROWS][128];
  __shared__ float zs[ROWS][132];  // padded to dodge bank conflicts on dot reads
  const int m0 = blockIdx.x * ROWS;
  const int tid = threadIdx.x;

  for (int idx = tid * 4; idx < ROWS * 128; idx += 256 * 4) {
    int r = idx >> 7;
    int d = idx & 127;
    *reinterpret_cast<float4*>(&xs[r][d]) =
        *reinterpret_cast<const float4*>(h + (m0 + r) * Hc + d);
  }
  __syncthreads();

  const int o = tid & 127;
  const int rg = tid >> 7;
  float acc[8] = {0, 0, 0, 0, 0, 0, 0, 0};
  const float* wrow = W1 + o * 128;
#pragma unroll 2
  for (int k = 0; k < 128; k += 4) {
    float4 w = *reinterpret_cast<const float4*>(wrow + k);
#pragma unroll
    for (int r = 0; r < 8; ++r) {
      const float* xr = &xs[rg * 8 + r][k];
      acc[r] += w.x * xr[0] + w.y * xr[1] + w.z * xr[2] + w.w * xr[3];
    }
  }
  const float bo = b1[o];
#pragma unroll
  for (int r = 0; r < 8; ++r) {
    zs[rg * 8 + r][o] = fmaxf(acc[r] + bo, 0.f);
  }
  __syncthreads();

  // 16 rows x 5 logits = 80 dot products of length 128
  if (tid < ROWS * Ac) {
    const int r = tid / Ac;
    const int a = tid % Ac;
    const float* wrow2 = W2 + a * 128;
    float s = 0.f;
#pragma unroll 4
    for (int k = 0; k < 128; k += 4) {
      float4 w = *reinterpret_cast<const float4*>(wrow2 + k);
      s += w.x * zs[r][k] + w.y * zs[r][k + 1] + w.z * zs[r][k + 2] + w.w * zs[r][k + 3];
    }
    out[(m0 + r) * Ac + a] = s + b2[a];
  }
}

// ---------------------------------------------------------------------------
extern "C" void kernel_launch(void* const* d_in, const int* in_sizes, int n_in,
                              void* d_out, int out_size, void* d_ws, size_t ws_size,
                              hipStream_t stream) {
  const float* theta = (const float*)d_in[0];   // (8,256,128)
  const float* cell  = (const float*)d_in[1];   // (8,256,128)
  const float* encW  = (const float*)d_in[2];   // (128,256)
  const float* encb  = (const float*)d_in[3];   // (128,)
  const float* msgW  = (const float*)d_in[4];   // (2,128,256)
  const float* msgb  = (const float*)d_in[5];   // (2,128)
  const float* updW  = (const float*)d_in[6];   // (2,128,128)
  const float* updb  = (const float*)d_in[7];   // (2,128)
  const float* hW1   = (const float*)d_in[8];   // (128,128)
  const float* hb1   = (const float*)d_in[9];   // (128,)
  const float* hW2   = (const float*)d_in[10];  // (5,128)
  const float* hb2   = (const float*)d_in[11];  // (5,)
  float* out = (float*)d_out;                   // (8,256,5) fp32

  float* ws = (float*)d_ws;
  const int MH = Mc * Hc;  // 262144
  float* h   = ws;
  float* pj  = ws + MH;
  float* pi  = ws + 2 * MH;
  float* agg = ws + 3 * MH;

  enc_kernel<<<Mc / ROWS, 256, 0, stream>>>(theta, cell, encW, encb, h);
  for (int l = 0; l < 2; ++l) {
    pjpi_kernel<<<Mc / ROWS, 256, 0, stream>>>(h, msgW + l * Hc * 2 * Hc, pj, pi);
    agg_kernel<<<Bc * (Nc / 8), 256, 0, stream>>>(pj, pi, msgb + l * Hc, agg);
    upd_kernel<<<Mc / ROWS, 256, 0, stream>>>(h, agg, updW + l * Hc * Hc,
                                              updb + l * Hc);
  }
  head_kernel<<<Mc / ROWS, 256, 0, stream>>>(h, hW1, hb1, hW2, hb2, out);
}

// Round 2
// 65.947 us; speedup vs baseline: 1.6380x; 1.6380x over previous
//
#include <hip/hip_runtime.h>
#include <hip/hip_bf16.h>

// AgentModel: B=8, N=256, TD=128, LH=128, H=128, A=5, L=2
constexpr int Bc = 8;
constexpr int Nc = 256;
constexpr int Hc = 128;
constexpr int Ac = 5;
constexpr int Mc = Bc * Nc;  // 2048
constexpr int R = 8;         // rows per block

// ---------------------------------------------------------------------------
// K1: encoder + pj/pi of layer 0.
// Block: 8 rows, 256 threads. enc: (o, rowgroup) threads; pjpi: 256 output
// cols (pj o<128, pi o>=128), h read from LDS (wave-broadcast).
// ---------------------------------------------------------------------------
__global__ __launch_bounds__(256) void k1_enc_pjpi(
    const float* __restrict__ theta, const float* __restrict__ cell,
    const float* __restrict__ encW, const float* __restrict__ encb,
    const float* __restrict__ msgW, float* __restrict__ h,
    float* __restrict__ pj, float* __restrict__ pi) {
  __shared__ float xs[R][256];
  __shared__ float hs[R][Hc];
  const int m0 = blockIdx.x * R;
  const int tid = threadIdx.x;

  // stage x = [theta | cell], 8 rows x 256, float4 coalesced
  for (int idx = tid * 4; idx < R * 256; idx += 256 * 4) {
    int r = idx >> 8, d = idx & 255;
    const float* src = (d < 128) ? theta + (m0 + r) * 128 + d
                                 : cell + (m0 + r) * 128 + (d - 128);
    *reinterpret_cast<float4*>(&xs[r][d]) = *reinterpret_cast<const float4*>(src);
  }
  __syncthreads();

  const int o = tid & 127;
  const int rg = tid >> 7;  // 2 groups x 4 rows
  {
    float acc[4] = {0, 0, 0, 0};
    const float* wr = encW + o * 256;
#pragma unroll 4
    for (int k = 0; k < 256; k += 4) {
      float4 w = *reinterpret_cast<const float4*>(wr + k);
#pragma unroll
      for (int r = 0; r < 4; ++r) {
        const float* x = &xs[rg * 4 + r][k];
        acc[r] += w.x * x[0] + w.y * x[1] + w.z * x[2] + w.w * x[3];
      }
    }
    const float b = encb[o];
#pragma unroll
    for (int r = 0; r < 4; ++r) {
      float v = fmaxf(acc[r] + b, 0.f);
      hs[rg * 4 + r][o] = v;
      h[(m0 + rg * 4 + r) * Hc + o] = v;
    }
  }
  __syncthreads();

  {  // pj / pi (layer 0)
    const float* wr = (tid < 128) ? msgW + tid * 256 : msgW + (tid - 128) * 256 + 128;
    float acc[R];
#pragma unroll
    for (int r = 0; r < R; ++r) acc[r] = 0.f;
#pragma unroll 2
    for (int k = 0; k < 128; k += 4) {
      float4 w = *reinterpret_cast<const float4*>(wr + k);
#pragma unroll
      for (int r = 0; r < R; ++r) {
        const float* x = &hs[r][k];
        acc[r] += w.x * x[0] + w.y * x[1] + w.z * x[2] + w.w * x[3];
      }
    }
    float* dst = (tid < 128) ? pj : pi;
    const int oc = tid & 127;
#pragma unroll
    for (int r = 0; r < R; ++r) dst[(m0 + r) * Hc + oc] = acc[r];
  }
}

// ---------------------------------------------------------------------------
// K2/K3: agg(l) + upd(l) [+ pjpi(l+1) | + head]
// agg via abs identity: sum_j relu(v+s) = 0.5*(P + N*s + sum_j|v+s|)
// pj reads are coalesced (lanes = o) and L2-resident; no LDS staging needed.
// ---------------------------------------------------------------------------
template <bool LAST>
__global__ __launch_bounds__(256) void k_layer(
    const float* __restrict__ pj, const float* __restrict__ pi,
    const float* __restrict__ mb, float* __restrict__ h,
    const float* __restrict__ updWl, const float* __restrict__ updbl,
    const float* __restrict__ msgW2, float* __restrict__ pj2,
    float* __restrict__ pi2, const float* __restrict__ hW1,
    const float* __restrict__ hb1, const float* __restrict__ hW2,
    const float* __restrict__ hb2, float* __restrict__ out) {
  __shared__ float xs[R][Hc];  // h + agg, later z
  __shared__ float hs[R][Hc];  // updated h
  const int m0 = blockIdx.x * R;
  const int b = m0 >> 8;  // Nc = 256
  const int tid = threadIdx.x;
  const int o = tid & 127;
  const int rg = tid >> 7;

  const float* pjb = pj + b * Nc * Hc;
  const float mbo = mb[o];

  float s[4], acc[4];
#pragma unroll
  for (int r = 0; r < 4; ++r) {
    s[r] = pi[(m0 + rg * 4 + r) * Hc + o] + mbo;
    acc[r] = 0.f;
  }
  float vsum = 0.f;
#pragma unroll 8
  for (int j = 0; j < Nc; ++j) {
    float v = pjb[j * Hc + o];  // coalesced, L2-hot
    vsum += v;
#pragma unroll
    for (int r = 0; r < 4; ++r) acc[r] += fabsf(v + s[r]);
  }
#pragma unroll
  for (int r = 0; r < 4; ++r) {
    const int row = rg * 4 + r;
    const int m = m0 + row;
    float diag = fmaxf(pjb[m % (Nc * Hc) / Hc * Hc + (m * Hc + o) % Hc], 0.f);
    // simpler: diag value = relu(pj[m,o] + s[r])
    diag = fmaxf(pj[m * Hc + o] + s[r], 0.f);
    float sumrelu = 0.5f * (vsum + 256.f * s[r] + acc[r]);
    float a = (sumrelu - diag) * (1.f / 255.f);
    xs[row][o] = h[m * Hc + o] + a;
  }
  __syncthreads();

  {  // upd GEMM
    float acc2[4] = {0, 0, 0, 0};
    const float* wr = updWl + o * Hc;
#pragma unroll 2
    for (int k = 0; k < 128; k += 4) {
      float4 w = *reinterpret_cast<const float4*>(wr + k);
#pragma unroll
      for (int r = 0; r < 4; ++r) {
        const float* x = &xs[rg * 4 + r][k];
        acc2[r] += w.x * x[0] + w.y * x[1] + w.z * x[2] + w.w * x[3];
      }
    }
    const float bo = updbl[o];
#pragma unroll
    for (int r = 0; r < 4; ++r) {
      float v = fmaxf(acc2[r] + bo, 0.f);
      hs[rg * 4 + r][o] = v;
      if (!LAST) h[(m0 + rg * 4 + r) * Hc + o] = v;
    }
  }
  __syncthreads();

  if (!LAST) {  // pj/pi of next layer from hs
    const float* wr =
        (tid < 128) ? msgW2 + tid * 256 : msgW2 + (tid - 128) * 256 + 128;
    float acc3[R];
#pragma unroll
    for (int r = 0; r < R; ++r) acc3[r] = 0.f;
#pragma unroll 2
    for (int k = 0; k < 128; k += 4) {
      float4 w = *reinterpret_cast<const float4*>(wr + k);
#pragma unroll
      for (int r = 0; r < R; ++r) {
        const float* x = &hs[r][k];
        acc3[r] += w.x * x[0] + w.y * x[1] + w.z * x[2] + w.w * x[3];
      }
    }
    float* dst = (tid < 128) ? pj2 : pi2;
    const int oc = tid & 127;
#pragma unroll
    for (int r = 0; r < R; ++r) dst[(m0 + r) * Hc + oc] = acc3[r];
  } else {  // head: z = relu(hs @ W1^T + b1) -> xs; logits = z @ W2^T + b2
    float acc3[4] = {0, 0, 0, 0};
    const float* wr = hW1 + o * Hc;
#pragma unroll 2
    for (int k = 0; k < 128; k += 4) {
      float4 w = *reinterpret_cast<const float4*>(wr + k);
#pragma unroll
      for (int r = 0; r < 4; ++r) {
        const float* x = &hs[rg * 4 + r][k];
        acc3[r] += w.x * x[0] + w.y * x[1] + w.z * x[2] + w.w * x[3];
      }
    }
    const float bo = hb1[o];
#pragma unroll
    for (int r = 0; r < 4; ++r) xs[rg * 4 + r][o] = fmaxf(acc3[r] + bo, 0.f);
    __syncthreads();

    if (tid < R * Ac) {  // 40 dot products of length 128
      const int r = tid / Ac;
      const int a = tid % Ac;
      const float* wr2 = hW2 + a * Hc;
      float sacc = 0.f;
#pragma unroll 4
      for (int k = 0; k < 128; k += 4) {
        float4 w = *reinterpret_cast<const float4*>(wr2 + k);
        sacc += w.x * xs[r][k] + w.y * xs[r][k + 1] + w.z * xs[r][k + 2] +
                w.w * xs[r][k + 3];
      }
      out[(m0 + r) * Ac + a] = sacc + hb2[a];
    }
  }
}

// ---------------------------------------------------------------------------
extern "C" void kernel_launch(void* const* d_in, const int* in_sizes, int n_in,
                              void* d_out, int out_size, void* d_ws, size_t ws_size,
                              hipStream_t stream) {
  const float* theta = (const float*)d_in[0];
  const float* cell  = (const float*)d_in[1];
  const float* encW  = (const float*)d_in[2];
  const float* encb  = (const float*)d_in[3];
  const float* msgW  = (const float*)d_in[4];   // (2,128,256)
  const float* msgb  = (const float*)d_in[5];   // (2,128)
  const float* updW  = (const float*)d_in[6];   // (2,128,128)
  const float* updb  = (const float*)d_in[7];   // (2,128)
  const float* hW1   = (const float*)d_in[8];
  const float* hb1   = (const float*)d_in[9];
  const float* hW2   = (const float*)d_in[10];
  const float* hb2   = (const float*)d_in[11];
  float* out = (float*)d_out;

  float* ws = (float*)d_ws;
  const int MH = Mc * Hc;
  float* h  = ws;
  float* pj = ws + MH;
  float* pi = ws + 2 * MH;

  const int grid = Mc / R;  // 256
  k1_enc_pjpi<<<grid, 256, 0, stream>>>(theta, cell, encW, encb, msgW, h, pj, pi);
  k_layer<false><<<grid, 256, 0, stream>>>(pj, pi, msgb, h, updW, updb,
                                           msgW + Hc * 2 * Hc, pj, pi, hW1, hb1,
                                           hW2, hb2, out);
  k_layer<true><<<grid, 256, 0, stream>>>(pj, pi, msgb + Hc, h, updW + Hc * Hc,
                                          updb + Hc, nullptr, nullptr, nullptr,
                                          hW1, hb1, hW2, hb2, out);
}